// Round 7
// baseline (1057.593 us; speedup 1.0000x reference)
//
#include <hip/hip_runtime.h>
#include <math.h>

#define NPROP 512
#define NB 2
#define NROWS (NB*NPROP)          // 1024
#define FCH 256
#define FH 64
#define FW 64
#define INDIM (FCH*7*7)           // 12544
#define HID 1024
#define NCLS 81
#define CAND_PER_IMG (NPROP*(NCLS-1))  // 40960
#define CLIPV 4.1351666f          // log(1000/16) rounded to f32

typedef _Float16 f16x8 __attribute__((ext_vector_type(8)));
typedef float f32x4 __attribute__((ext_vector_type(4)));
typedef unsigned int u32;
typedef unsigned long long u64;

// ---- workspace layout (bytes) ----
#define XHI_OFF    0ull
#define XLO_OFF    25690112ull
#define WT1HI_OFF  51380224ull
#define WT1LO_OFF  77070336ull
#define WT2HI_OFF  102760448ull
#define WT2LO_OFF  104857600ull
#define H1HI_OFF   106954752ull
#define H1LO_OFF   109051904ull
#define H2_OFF     111149056ull
#define CWT_OFF    115343360ull
#define BWT_OFF    116338688ull
#define PROBS_OFF  116387840ull
#define CUR_OFF    116719616ull
#define CNT_OFF    116736000ull   // ccnt[160] ints
#define CCS_OFF    116737024ull   // per-class scores   [160][512] f32
#define CCOB_OFF   117064704ull   // per-class off-box  [160][512] float4
#define CCAR_OFF   118375424ull   // per-class area     [160][512] f32
#define CCBX_OFF   118703104ull   // per-class box      [160][512] float4
#define CCIX_OFF   120013824ull   // per-class coidx    [160][512] int
#define SVS_OFF    120341504ull   // survivors score    [160][128] f32
#define SVB_OFF    120423424ull   // survivors box      [160][128] float4
#define SVI_OFF    120751104ull   // survivors coidx    [160][128] int
#define SVC_OFF    120833024ull   // survivor count     [160] int
#define PART_OFF   121489408ull   // 8 planes of 1024x1024 f32 = 33.5 MB

__global__ void init_kernel(int* ccnt) {
    if (threadIdx.x < 160) ccnt[threadIdx.x] = 0;
}

// one block per (b,n) proposal; writes scaled f16 limb planes of X
__global__ __launch_bounds__(256) void roi_align_kernel(
    const float* __restrict__ feat, const float* __restrict__ boxes,
    _Float16* __restrict__ Xhi, _Float16* __restrict__ Xlo)
{
    int r = blockIdx.x;           // b*512+n
    int b = r >> 9;
    const float* f = feat + (size_t)b * (FCH*FH*FW);
    __shared__ float sb[4];
    __shared__ int   sx0[49], sx1[49], sy0[49], sy1[49];
    __shared__ float sw00[49], sw01[49], sw10[49], sw11[49];
    int tid = threadIdx.x;
    if (tid == 0) {
        float x1 = boxes[r*4+0]*0.125f, y1 = boxes[r*4+1]*0.125f;
        float x2 = boxes[r*4+2]*0.125f, y2 = boxes[r*4+3]*0.125f;
        sb[0] = x1; sb[1] = y1;
        sb[2] = fmaxf(x2-x1, 1.0f) / 7.0f;   // bw
        sb[3] = fmaxf(y2-y1, 1.0f) / 7.0f;   // bh
    }
    __syncthreads();
    if (tid < 49) {
        int py = tid / 7, px = tid - py*7;
        float gx = sb[0] + ((float)px + 0.5f)*sb[2];
        float gy = sb[1] + ((float)py + 0.5f)*sb[3];
        gx = fminf(fmaxf(gx, 0.0f), 63.0f);
        gy = fminf(fmaxf(gy, 0.0f), 63.0f);
        float x0f = floorf(gx), y0f = floorf(gy);
        int x0 = (int)x0f, y0 = (int)y0f;
        sx0[tid] = x0; sy0[tid] = y0;
        sx1[tid] = min(x0+1, 63); sy1[tid] = min(y0+1, 63);
        float dx = gx - x0f, dy = gy - y0f;
        sw00[tid] = (1.0f-dy)*(1.0f-dx);
        sw01[tid] = (1.0f-dy)*dx;
        sw10[tid] = dy*(1.0f-dx);
        sw11[tid] = dy*dx;
    }
    __syncthreads();
    size_t xbase = (size_t)r * INDIM;
    for (int i = tid; i < INDIM; i += 256) {
        int c = i / 49;
        int p = i - c*49;
        const float* fc = f + c*(FH*FW);
        int r0 = sy0[p]*FW, r1 = sy1[p]*FW;
        float v = fc[r0 + sx0[p]]*sw00[p] + fc[r0 + sx1[p]]*sw01[p]
                + fc[r1 + sx0[p]]*sw10[p] + fc[r1 + sx1[p]]*sw11[p];
        float vs = v * 32.0f;
        _Float16 h = (_Float16)vs;
        Xhi[xbase + i] = h;
        Xlo[xbase + i] = (_Float16)(vs - (float)h);
    }
}

// in [K][N] fp32 -> hi/lo [N][K] f16 (scaled). K,N multiples of 32.
__global__ __launch_bounds__(256) void trans_limb(
    const float* __restrict__ in, _Float16* __restrict__ hi, _Float16* __restrict__ lo,
    int K, int N, float scale)
{
    __shared__ float t[32][33];
    int tx = threadIdx.x & 31, ty = threadIdx.x >> 5;   // ty 0..7
    int n0 = blockIdx.x << 5, k0 = blockIdx.y << 5;
#pragma unroll
    for (int r = 0; r < 4; ++r)
        t[ty + 8*r][tx] = in[(size_t)(k0 + ty + 8*r)*N + n0 + tx];
    __syncthreads();
#pragma unroll
    for (int r = 0; r < 4; ++r) {
        int n = n0 + ty + 8*r, k = k0 + tx;
        float v = t[tx][ty + 8*r] * scale;
        _Float16 h = (_Float16)v;
        hi[(size_t)n*K + k] = h;
        lo[(size_t)n*K + k] = (_Float16)(v - (float)h);
    }
}

// batched plain transpose: in [b][K][N] -> out [b][N][K] (fp32, small)
__global__ __launch_bounds__(256) void trans_naive(
    const float* __restrict__ in, float* __restrict__ out, int K, int N, int batch)
{
    int idx = blockIdx.x*256 + threadIdx.x;
    int per = K*N;
    if (idx >= per*batch) return;
    int b = idx / per;
    int rem = idx - b*per;
    int n = rem / K, k = rem - n*K;
    out[idx] = in[(size_t)b*per + (size_t)k*N + n];
}

// ---------------------------------------------------------------------------
// f16-limb MFMA split-K GEMM -- REGISTER-DIRECT: no LDS, no barriers, no asm.
// Each lane's MFMA fragment is 16 contiguous bytes of the [M][K]/[N][K] limb
// planes, so fragments load straight to VGPRs (global_load_dwordx4). Depth-1
// double-buffered fragments (F0/F1, explicit 2-step unroll); compiler manages
// vmcnt per frag and overlaps next-step loads under the 48-MFMA block.
// L1 catches the 2x intra-block sibling reuse; XCD-affine z keeps L2 warm.
// 128x128 block tile, 4 waves (2x2), wave 64x64 = 4x4 frags of 16x16x32.
// ---------------------------------------------------------------------------
struct Frags { f16x8 Ah[4], Al[4], Bh[4], Bl[4]; };

__device__ __forceinline__ void loadf(
    Frags& F, const _Float16* pAh, const _Float16* pAl,
    const _Float16* pBh, const _Float16* pBl, size_t KS, int koff)
{
#pragma unroll
    for (int i = 0; i < 4; ++i) {
        F.Ah[i] = *(const f16x8*)(pAh + i*KS + koff);
        F.Al[i] = *(const f16x8*)(pAl + i*KS + koff);
        F.Bh[i] = *(const f16x8*)(pBh + i*KS + koff);
        F.Bl[i] = *(const f16x8*)(pBl + i*KS + koff);
    }
}

__device__ __forceinline__ void mfma16(Frags& F, f32x4 (&acc)[4][4]) {
#pragma unroll
    for (int mi = 0; mi < 4; ++mi)
#pragma unroll
        for (int ni = 0; ni < 4; ++ni) {
            acc[mi][ni] = __builtin_amdgcn_mfma_f32_16x16x32_f16(F.Ah[mi], F.Bh[ni], acc[mi][ni], 0, 0, 0);
            acc[mi][ni] = __builtin_amdgcn_mfma_f32_16x16x32_f16(F.Ah[mi], F.Bl[ni], acc[mi][ni], 0, 0, 0);
            acc[mi][ni] = __builtin_amdgcn_mfma_f32_16x16x32_f16(F.Al[mi], F.Bh[ni], acc[mi][ni], 0, 0, 0);
        }
}

__global__ __launch_bounds__(256, 1) void mfma_gemm_limb(
    const _Float16* __restrict__ Ahi, const _Float16* __restrict__ Alo,
    const _Float16* __restrict__ Bhi, const _Float16* __restrict__ Blo,
    float* __restrict__ part, int K, int base, int extra, int lognz)
{
    const int tid = threadIdx.x;
    const int lane = tid & 63;
    const int w = tid >> 6, wm = w >> 1, wn = w & 1;
    const int kg = lane >> 4, lr = lane & 15;
    const int bid = blockIdx.x;
    const int nzm = (1 << lognz) - 1;
    const int z = bid & nzm;
    const int bx = (bid >> lognz) & 7;
    const int by = bid >> (lognz + 3);
    const int row0 = by << 7, col0 = bx << 7;
    const int zsteps = base + (z < extra ? 1 : 0);
    const int kb0 = (z*base + (z < extra ? z : extra)) * 32;

    // per-lane fragment base pointers (frag mi/ni at +i*16*K, step t at +t*32)
    const size_t aoff = (size_t)(row0 + wm*64 + lr) * K + kb0 + kg*8;
    const size_t boff = (size_t)(col0 + wn*64 + lr) * K + kb0 + kg*8;
    const _Float16* pAh = Ahi + aoff;
    const _Float16* pAl = Alo + aoff;
    const _Float16* pBh = Bhi + boff;
    const _Float16* pBl = Blo + boff;
    const size_t KS = (size_t)K * 16;

    f32x4 acc[4][4];
#pragma unroll
    for (int i = 0; i < 4; ++i)
#pragma unroll
        for (int j = 0; j < 4; ++j) acc[i][j] = (f32x4){0.f, 0.f, 0.f, 0.f};

    Frags F0, F1;
    loadf(F0, pAh, pAl, pBh, pBl, KS, 0);
    int t = 0;
    while (t < zsteps) {
        if (t + 1 < zsteps) loadf(F1, pAh, pAl, pBh, pBl, KS, (t+1)*32);
        mfma16(F0, acc);
        ++t;
        if (t >= zsteps) break;
        if (t + 1 < zsteps) loadf(F0, pAh, pAl, pBh, pBl, KS, (t+1)*32);
        mfma16(F1, acc);
        ++t;
    }

    // epilogue: C/D layout col=lane&15, row=(lane>>4)*4+j
    float* cb = part + ((size_t)z << 20)
              + (size_t)row0*HID + col0 + wn*64 + lr;
#pragma unroll
    for (int mi = 0; mi < 4; ++mi) {
#pragma unroll
        for (int j = 0; j < 4; ++j) {
            int row = wm*64 + mi*16 + kg*4 + j;
            float* pr = cb + (size_t)row*HID;
            pr[0]  = acc[mi][0][j];
            pr[16] = acc[mi][1][j];
            pr[32] = acc[mi][2][j];
            pr[48] = acc[mi][3][j];
        }
    }
}

// out = relu(sum_p part[p]/2048 + bias); mode 0: fp32 out; mode 1: f16 limb out (x32)
__global__ __launch_bounds__(256) void reduce_bias_relu(
    const float* __restrict__ part, const float* __restrict__ bias,
    float* __restrict__ out32, _Float16* __restrict__ outhi, _Float16* __restrict__ outlo,
    int nsplit, int mode)
{
    int gid = blockIdx.x*256 + threadIdx.x;
    float s = 0.f;
    for (int p = 0; p < nsplit; ++p) s += part[((size_t)p << 20) + gid];
    s = s * (1.0f/2048.0f) + bias[gid & (HID-1)];
    s = fmaxf(s, 0.f);
    if (mode == 0) {
        out32[gid] = s;
    } else {
        float vs = s * 32.0f;
        _Float16 h = (_Float16)vs;
        outhi[gid] = h;
        outlo[gid] = (_Float16)(vs - (float)h);
    }
}

// cls+bbox heads + decode (+softmax at last stage). 4 rows per block.
__global__ __launch_bounds__(512) void heads_kernel(
    const float* __restrict__ X, const float* __restrict__ cwT, const float* __restrict__ cb,
    const float* __restrict__ bwT, const float* __restrict__ bbb,
    float* __restrict__ cur, float* __restrict__ probs,
    const int* __restrict__ img_sz, int stage, int write_probs)
{
    __shared__ float xs[4][1024];
    __shared__ float lg[4][96];
    int tid = threadIdx.x;
    int lr = tid >> 7;           // local row 0..3
    int j  = tid & 127;
    int row0 = blockIdx.x * 4;
    for (int i = tid; i < 4096; i += 512)
        xs[i >> 10][i & 1023] = X[(size_t)(row0 + (i >> 10))*1024 + (i & 1023)];
    __syncthreads();
    int row = row0 + lr;
    if (j < 85) {
        const float* wrow = (j < 81) ? (cwT + (size_t)j*HID) : (bwT + (size_t)(j-81)*HID);
        float acc = (j < 81) ? cb[j] : bbb[j-81];
        const float4* w4 = (const float4*)wrow;
#pragma unroll 4
        for (int k4 = 0; k4 < 256; ++k4) {
            float4 wv = w4[k4];
            const float* xr = &xs[lr][k4*4];
            acc = fmaf(xr[0], wv.x, acc);
            acc = fmaf(xr[1], wv.y, acc);
            acc = fmaf(xr[2], wv.z, acc);
            acc = fmaf(xr[3], wv.w, acc);
        }
        lg[lr][j] = acc;
    }
    __syncthreads();
    if (j == 0) {   // box decode + clip
        float img = (float)(*img_sz);
        float px1 = cur[row*4+0], py1 = cur[row*4+1];
        float px2 = cur[row*4+2], py2 = cur[row*4+3];
        float pw = fmaxf(px2-px1, 1e-6f), ph = fmaxf(py2-py1, 1e-6f);
        float pcx = px1 + 0.5f*pw, pcy = py1 + 0.5f*ph;
        float wx, wy, ww, wh;
        if (stage == 0)      { wx=0.1f;   wy=0.1f;   ww=0.2f;   wh=0.2f;   }
        else if (stage == 1) { wx=0.05f;  wy=0.05f;  ww=0.1f;   wh=0.1f;   }
        else                 { wx=0.033f; wy=0.033f; ww=0.067f; wh=0.067f; }
        float dx = lg[lr][81]*wx, dy = lg[lr][82]*wy;
        float dw = fminf(lg[lr][83]*ww, CLIPV);
        float dh = fminf(lg[lr][84]*wh, CLIPV);
        float cx = dx*pw + pcx, cy = dy*ph + pcy;
        float w = expf(dw)*pw, h = expf(dh)*ph;
        cur[row*4+0] = fminf(fmaxf(cx - 0.5f*w, 0.f), img);
        cur[row*4+1] = fminf(fmaxf(cy - 0.5f*h, 0.f), img);
        cur[row*4+2] = fminf(fmaxf(cx + 0.5f*w, 0.f), img);
        cur[row*4+3] = fminf(fmaxf(cy + 0.5f*h, 0.f), img);
    }
    if (write_probs) {
        if (j == 1) {
            float m = lg[lr][0];
            for (int c2 = 1; c2 < 81; ++c2) m = fmaxf(m, lg[lr][c2]);
            float s = 0.f;
            for (int c2 = 0; c2 < 81; ++c2) s += expf(lg[lr][c2] - m);
            lg[lr][88] = m; lg[lr][89] = s;
        }
        __syncthreads();
        if (j < 81)
            probs[(size_t)row*81 + j] = expf(lg[lr][j] - lg[lr][88]) / lg[lr][89];
    }
}

// bucket passing candidates per (image,class); cross-class IoU is exactly 0
// (label offset trick), so NMS decomposes per class.
__global__ __launch_bounds__(256) void compact_class(
    const float* __restrict__ probs, const float* __restrict__ cur,
    const int* __restrict__ img_sz, int* __restrict__ ccnt,
    float* __restrict__ ccs, float4* __restrict__ ccob, float* __restrict__ ccar,
    float4* __restrict__ ccbx, int* __restrict__ ccix)
{
    int gid = blockIdx.x*256 + threadIdx.x;
    if (gid >= NB*CAND_PER_IMG) return;
    int b = gid / CAND_PER_IMG;
    int rem = gid - b*CAND_PER_IMG;
    int n = rem / 80;
    int cm = rem - n*80;
    int label = cm + 1;
    int r = b*NPROP + n;
    float s = probs[(size_t)r*81 + label];
    float b0 = cur[r*4+0], b1 = cur[r*4+1], b2 = cur[r*4+2], b3 = cur[r*4+3];
    if (s > 0.05f && (b2 - b0) >= 1.0f && (b3 - b1) >= 1.0f) {
        int cls = b*80 + cm;
        int pos = atomicAdd(&ccnt[cls], 1);
        int base = cls*512 + pos;
        float img = (float)(*img_sz);
        float t = (float)label * (img + 2.0f);
        float o0 = b0+t, o1 = b1+t, o2 = b2+t, o3 = b3+t;
        ccs[base] = s;
        ccob[base] = make_float4(o0, o1, o2, o3);
        ccar[base] = fmaxf(o2-o0, 0.f) * fmaxf(o3-o1, 0.f);
        ccbx[base] = make_float4(b0, b1, b2, b3);
        ccix[base] = rem;   // reference flat order for tie-break
    }
}

// one wave per (image,class): greedy NMS entirely in registers
__global__ __launch_bounds__(64) void class_nms(
    const int* __restrict__ ccnt, const float* __restrict__ ccs,
    const float4* __restrict__ ccob, const float* __restrict__ ccar,
    const float4* __restrict__ ccbx, const int* __restrict__ ccix,
    float* __restrict__ svs, float4* __restrict__ svb, int* __restrict__ svi,
    int* __restrict__ svc)
{
    int cls = blockIdx.x;          // 0..159
    int Nc = ccnt[cls];
    int base = cls*512;
    int lane = threadIdx.x;
    __shared__ float sel[5];
    float s[8]; float4 ob[8]; float a[8]; int ix[8];
    int cntl = 0;
    for (int j = lane; j < Nc; j += 64) {
        s[cntl] = ccs[base+j]; ob[cntl] = ccob[base+j];
        a[cntl] = ccar[base+j]; ix[cntl] = ccix[base+j];
        ++cntl;
    }
    int svn = 0;
    int rounds = (Nc < 100) ? Nc : 100;
    for (int it = 0; it < rounds; ++it) {
        float bs = -1.f; int bi = 0x7fffffff;
        for (int q = 0; q < cntl; ++q)
            if (s[q] > bs || (s[q] == bs && ix[q] < bi)) { bs = s[q]; bi = ix[q]; }
        for (int off = 32; off > 0; off >>= 1) {
            float os = __shfl_xor(bs, off);
            int oi = __shfl_xor(bi, off);
            if (os > bs || (os == bs && oi < bi)) { bs = os; bi = oi; }
        }
        if (bs <= 0.f) break;      // uniform across wave
        for (int q = 0; q < cntl; ++q) {
            if (s[q] == bs && ix[q] == bi) {   // unique owner (ix unique)
                sel[0] = ob[q].x; sel[1] = ob[q].y; sel[2] = ob[q].z; sel[3] = ob[q].w;
                sel[4] = a[q];
                int slot = cls*128 + svn;
                svs[slot] = bs;
                svb[slot] = ccbx[base + lane + q*64];
                svi[slot] = bi;
                s[q] = -1.f;
            }
        }
        __syncthreads();
        float bi0 = sel[0], bi1 = sel[1], bi2 = sel[2], bi3 = sel[3], ai = sel[4];
        for (int q = 0; q < cntl; ++q) {
            if (s[q] > 0.f) {
                float ix1 = fmaxf(bi0, ob[q].x), iy1 = fmaxf(bi1, ob[q].y);
                float ix2 = fminf(bi2, ob[q].z), iy2 = fminf(bi3, ob[q].w);
                float inter = fmaxf(ix2-ix1, 0.f) * fmaxf(iy2-iy1, 0.f);
                float iou = inter / (ai + a[q] - inter + 1e-9f);
                if (iou > 0.5f) s[q] = -1.f;
            }
        }
        ++svn;
        __syncthreads();
    }
    if (lane == 0) svc[cls] = svn;
}

// per image: bitonic-sort survivors by (score desc, coidx asc), write top-100.
// key = (score_bits << 32) | (~coidx); invalid slots key=0 sort last.
__global__ __launch_bounds__(256) void merge_topk(
    const float* __restrict__ svs, const float4* __restrict__ svb,
    const int* __restrict__ svi, const int* __restrict__ svc,
    float* __restrict__ out)
{
    extern __shared__ char smem[];
    u64* keys = (u64*)smem;                 // [8192] 64KB
    u32* pay  = (u32*)(smem + 65536);       // [8192] 32KB
    __shared__ int off[81];
    __shared__ int n2s;
    int b = blockIdx.x, tid = threadIdx.x;
    if (tid == 0) {
        int run = 0;
        for (int c = 0; c < 80; ++c) { off[c] = run; run += svc[b*80 + c]; }
        off[80] = run;
        int n2 = 256;
        while (n2 < run) n2 <<= 1;
        n2s = n2;
    }
    __syncthreads();
    int Ns = off[80], n2 = n2s;
    for (int c = 0; c < 80; ++c) {
        int n = off[c+1] - off[c];
        int srcb = (b*80 + c)*128;
        for (int k = tid; k < n; k += 256) {
            int src = srcb + k;
            keys[off[c] + k] = ((u64)__float_as_uint(svs[src]) << 32)
                             | (u64)(0xFFFFFFFFu - (u32)svi[src]);
            pay[off[c] + k] = src;
        }
    }
    for (int i = Ns + tid; i < n2; i += 256) { keys[i] = 0; pay[i] = 0; }
    __syncthreads();
    for (int k = 2; k <= n2; k <<= 1) {
        for (int j = k >> 1; j > 0; j >>= 1) {
            for (int i = tid; i < n2; i += 256) {
                int l = i ^ j;
                if (l > i) {
                    u64 a = keys[i], bb = keys[l];
                    bool dir = ((i & k) == 0);
                    if ((a < bb) == dir) {
                        keys[i] = bb; keys[l] = a;
                        u32 p = pay[i]; pay[i] = pay[l]; pay[l] = p;
                    }
                }
            }
            __syncthreads();
        }
    }
    if (tid < 100) {
        u64 kk = keys[tid];      // n2 >= 256 > 100 always
        if (kk != 0) {
            u32 ci = 0xFFFFFFFFu - (u32)(kk & 0xFFFFFFFFull);
            float4 bx = svb[pay[tid]];
            out[b*400 + tid*4 + 0] = bx.x;
            out[b*400 + tid*4 + 1] = bx.y;
            out[b*400 + tid*4 + 2] = bx.z;
            out[b*400 + tid*4 + 3] = bx.w;
            out[800  + b*100 + tid] = __uint_as_float((u32)(kk >> 32));
            out[1000 + b*100 + tid] = (float)((ci % 80) + 1);
        } else {
            out[b*400 + tid*4 + 0] = 0.f; out[b*400 + tid*4 + 1] = 0.f;
            out[b*400 + tid*4 + 2] = 0.f; out[b*400 + tid*4 + 3] = 0.f;
            out[800  + b*100 + tid] = 0.f;
            out[1000 + b*100 + tid] = 0.f;
        }
    }
}

extern "C" void kernel_launch(void* const* d_in, const int* in_sizes, int n_in,
                              void* d_out, int out_size, void* d_ws, size_t ws_size,
                              hipStream_t stream)
{
    const float* features  = (const float*)d_in[0];
    const float* proposals = (const float*)d_in[1];
    const float* fc1_w = (const float*)d_in[2];
    const float* fc1_b = (const float*)d_in[3];
    const float* fc2_w = (const float*)d_in[4];
    const float* fc2_b = (const float*)d_in[5];
    const float* cls_w = (const float*)d_in[6];
    const float* cls_b = (const float*)d_in[7];
    const float* bbox_w = (const float*)d_in[8];
    const float* bbox_b = (const float*)d_in[9];
    const int* img_sz = (const int*)d_in[10];
    float* out = (float*)d_out;
    char* ws = (char*)d_ws;
    _Float16* xhi   = (_Float16*)(ws + XHI_OFF);
    _Float16* xlo   = (_Float16*)(ws + XLO_OFF);
    _Float16* wt1hi = (_Float16*)(ws + WT1HI_OFF);
    _Float16* wt1lo = (_Float16*)(ws + WT1LO_OFF);
    _Float16* wt2hi = (_Float16*)(ws + WT2HI_OFF);
    _Float16* wt2lo = (_Float16*)(ws + WT2LO_OFF);
    _Float16* h1hi  = (_Float16*)(ws + H1HI_OFF);
    _Float16* h1lo  = (_Float16*)(ws + H1LO_OFF);
    float*  h2     = (float*) (ws + H2_OFF);
    float*  cwT    = (float*) (ws + CWT_OFF);
    float*  bwT    = (float*) (ws + BWT_OFF);
    float*  probs  = (float*) (ws + PROBS_OFF);
    float*  cur    = (float*) (ws + CUR_OFF);
    int*    ccnt   = (int*)   (ws + CNT_OFF);
    float*  ccs    = (float*) (ws + CCS_OFF);
    float4* ccob   = (float4*)(ws + CCOB_OFF);
    float*  ccar   = (float*) (ws + CCAR_OFF);
    float4* ccbx   = (float4*)(ws + CCBX_OFF);
    int*    ccix   = (int*)   (ws + CCIX_OFF);
    float*  svs    = (float*) (ws + SVS_OFF);
    float4* svb    = (float4*)(ws + SVB_OFF);
    int*    svi    = (int*)   (ws + SVI_OFF);
    int*    svc    = (int*)   (ws + SVC_OFF);
    float*  part   = (float*) (ws + PART_OFF);

    init_kernel<<<1, 256, 0, stream>>>(ccnt);
    hipMemcpyAsync(cur, proposals, (size_t)NROWS*4*sizeof(float),
                   hipMemcpyDeviceToDevice, stream);
    trans_naive<<<(3*NCLS*HID + 255)/256, 256, 0, stream>>>(cls_w, cwT, HID, NCLS, 3);
    trans_naive<<<(3*4*HID + 255)/256, 256, 0, stream>>>(bbox_w, bwT, HID, 4, 3);

    for (int st = 0; st < 3; ++st) {
        roi_align_kernel<<<NROWS, 256, 0, stream>>>(features, cur, xhi, xlo);
        trans_limb<<<dim3(HID/32, INDIM/32), 256, 0, stream>>>(
            fc1_w + (size_t)st*INDIM*HID, wt1hi, wt1lo, INDIM, HID, 64.0f);
        // fc1: K=12544 = 392 K-steps; z=8 x 49 steps, grid 512 = 2 blocks/CU
        mfma_gemm_limb<<<512, 256, 0, stream>>>(
            xhi, xlo, wt1hi, wt1lo, part, INDIM, 49, 0, 3);
        reduce_bias_relu<<<(NROWS*HID)/256, 256, 0, stream>>>(
            part, fc1_b + st*HID, nullptr, h1hi, h1lo, 8, 1);
        trans_limb<<<dim3(HID/32, HID/32), 256, 0, stream>>>(
            fc2_w + (size_t)st*HID*HID, wt2hi, wt2lo, HID, HID, 64.0f);
        // fc2: K=1024 = 32 K-steps; z=8 x 4 steps
        mfma_gemm_limb<<<512, 256, 0, stream>>>(
            h1hi, h1lo, wt2hi, wt2lo, part, HID, 4, 0, 3);
        reduce_bias_relu<<<(NROWS*HID)/256, 256, 0, stream>>>(
            part, fc2_b + st*HID, h2, nullptr, nullptr, 8, 0);
        heads_kernel<<<NROWS/4, 512, 0, stream>>>(
            h2, cwT + (size_t)st*NCLS*HID, cls_b + st*NCLS,
            bwT + (size_t)st*4*HID, bbox_b + st*4,
            cur, probs, img_sz, st, st == 2 ? 1 : 0);
    }
    compact_class<<<(NB*CAND_PER_IMG)/256, 256, 0, stream>>>(
        probs, cur, img_sz, ccnt, ccs, ccob, ccar, ccbx, ccix);
    class_nms<<<160, 64, 0, stream>>>(
        ccnt, ccs, ccob, ccar, ccbx, ccix, svs, svb, svi, svc);
    merge_topk<<<NB, 256, 98304, stream>>>(
        svs, svb, svi, svc, out);
}

// Round 8
// 775.324 us; speedup vs baseline: 1.3641x; 1.3641x over previous
//
#include <hip/hip_runtime.h>
#include <math.h>

#define NPROP 512
#define NB 2
#define NROWS (NB*NPROP)          // 1024
#define FCH 256
#define FH 64
#define FW 64
#define INDIM (FCH*7*7)           // 12544
#define HID 1024
#define NCLS 81
#define CAND_PER_IMG (NPROP*(NCLS-1))  // 40960
#define CLIPV 4.1351666f          // log(1000/16) rounded to f32

typedef _Float16 f16x8 __attribute__((ext_vector_type(8)));
typedef float f32x4 __attribute__((ext_vector_type(4)));
typedef unsigned int u32;
typedef unsigned long long u64;

__device__ __forceinline__ void gload16(const void* g, void* l) {
    __builtin_amdgcn_global_load_lds((const __attribute__((address_space(1))) u32*)g,
                                     (__attribute__((address_space(3))) u32*)l, 16, 0, 0);
}

// ---- workspace layout (bytes) ----
#define XHI_OFF    0ull
#define XLO_OFF    25690112ull
#define WT1HI_OFF  51380224ull
#define WT1LO_OFF  77070336ull
#define WT2HI_OFF  102760448ull
#define WT2LO_OFF  104857600ull
#define H1HI_OFF   106954752ull
#define H1LO_OFF   109051904ull
#define H2_OFF     111149056ull
#define CWT_OFF    115343360ull
#define BWT_OFF    116338688ull
#define PROBS_OFF  116387840ull
#define CUR_OFF    116719616ull
#define CNT_OFF    116736000ull   // ccnt[160] ints
#define CCS_OFF    116737024ull   // per-class scores   [160][512] f32
#define CCOB_OFF   117064704ull   // per-class off-box  [160][512] float4
#define CCAR_OFF   118375424ull   // per-class area     [160][512] f32
#define CCBX_OFF   118703104ull   // per-class box      [160][512] float4
#define CCIX_OFF   120013824ull   // per-class coidx    [160][512] int
#define SVS_OFF    120341504ull   // survivors score    [160][128] f32
#define SVB_OFF    120423424ull   // survivors box      [160][128] float4
#define SVI_OFF    120751104ull   // survivors coidx    [160][128] int
#define SVC_OFF    120833024ull   // survivor count     [160] int
#define PART_OFF   121489408ull   // 16 planes of 1024x1024 f32 = 67 MB

__global__ void init_kernel(int* ccnt) {
    if (threadIdx.x < 160) ccnt[threadIdx.x] = 0;
}

// one block per (b,n) proposal; writes scaled f16 limb planes of X
__global__ __launch_bounds__(256) void roi_align_kernel(
    const float* __restrict__ feat, const float* __restrict__ boxes,
    _Float16* __restrict__ Xhi, _Float16* __restrict__ Xlo)
{
    int r = blockIdx.x;           // b*512+n
    int b = r >> 9;
    const float* f = feat + (size_t)b * (FCH*FH*FW);
    __shared__ float sb[4];
    __shared__ int   sx0[49], sx1[49], sy0[49], sy1[49];
    __shared__ float sw00[49], sw01[49], sw10[49], sw11[49];
    int tid = threadIdx.x;
    if (tid == 0) {
        float x1 = boxes[r*4+0]*0.125f, y1 = boxes[r*4+1]*0.125f;
        float x2 = boxes[r*4+2]*0.125f, y2 = boxes[r*4+3]*0.125f;
        sb[0] = x1; sb[1] = y1;
        sb[2] = fmaxf(x2-x1, 1.0f) / 7.0f;   // bw
        sb[3] = fmaxf(y2-y1, 1.0f) / 7.0f;   // bh
    }
    __syncthreads();
    if (tid < 49) {
        int py = tid / 7, px = tid - py*7;
        float gx = sb[0] + ((float)px + 0.5f)*sb[2];
        float gy = sb[1] + ((float)py + 0.5f)*sb[3];
        gx = fminf(fmaxf(gx, 0.0f), 63.0f);
        gy = fminf(fmaxf(gy, 0.0f), 63.0f);
        float x0f = floorf(gx), y0f = floorf(gy);
        int x0 = (int)x0f, y0 = (int)y0f;
        sx0[tid] = x0; sy0[tid] = y0;
        sx1[tid] = min(x0+1, 63); sy1[tid] = min(y0+1, 63);
        float dx = gx - x0f, dy = gy - y0f;
        sw00[tid] = (1.0f-dy)*(1.0f-dx);
        sw01[tid] = (1.0f-dy)*dx;
        sw10[tid] = dy*(1.0f-dx);
        sw11[tid] = dy*dx;
    }
    __syncthreads();
    size_t xbase = (size_t)r * INDIM;
    for (int i = tid; i < INDIM; i += 256) {
        int c = i / 49;
        int p = i - c*49;
        const float* fc = f + c*(FH*FW);
        int r0 = sy0[p]*FW, r1 = sy1[p]*FW;
        float v = fc[r0 + sx0[p]]*sw00[p] + fc[r0 + sx1[p]]*sw01[p]
                + fc[r1 + sx0[p]]*sw10[p] + fc[r1 + sx1[p]]*sw11[p];
        float vs = v * 32.0f;
        _Float16 h = (_Float16)vs;
        Xhi[xbase + i] = h;
        Xlo[xbase + i] = (_Float16)(vs - (float)h);
    }
}

// in [K][N] fp32 -> hi/lo [N][K] f16 (scaled). K,N multiples of 32.
__global__ __launch_bounds__(256) void trans_limb(
    const float* __restrict__ in, _Float16* __restrict__ hi, _Float16* __restrict__ lo,
    int K, int N, float scale)
{
    __shared__ float t[32][33];
    int tx = threadIdx.x & 31, ty = threadIdx.x >> 5;   // ty 0..7
    int n0 = blockIdx.x << 5, k0 = blockIdx.y << 5;
#pragma unroll
    for (int r = 0; r < 4; ++r)
        t[ty + 8*r][tx] = in[(size_t)(k0 + ty + 8*r)*N + n0 + tx];
    __syncthreads();
#pragma unroll
    for (int r = 0; r < 4; ++r) {
        int n = n0 + ty + 8*r, k = k0 + tx;
        float v = t[tx][ty + 8*r] * scale;
        _Float16 h = (_Float16)v;
        hi[(size_t)n*K + k] = h;
        lo[(size_t)n*K + k] = (_Float16)(v - (float)h);
    }
}

// batched plain transpose: in [b][K][N] -> out [b][N][K] (fp32, small)
__global__ __launch_bounds__(256) void trans_naive(
    const float* __restrict__ in, float* __restrict__ out, int K, int N, int batch)
{
    int idx = blockIdx.x*256 + threadIdx.x;
    int per = K*N;
    if (idx >= per*batch) return;
    int b = idx / per;
    int rem = idx - b*per;
    int n = rem / K, k = rem - n*K;
    out[idx] = in[(size_t)b*per + (size_t)k*N + n];
}

// ---------------------------------------------------------------------------
// fc1 GEMM: 256x256 tile, 8 waves (2x4), f16-limb MFMA, 128KB dynamic-LDS
// double buffer, counted vmcnt(8), raw barriers + compiler memory fences.
// Per K-step per CU: 64KB staged over ~3726cyc MFMA window = 17.6 B/cyc
// (4x under L2 ceiling -- fixes r6's 70 B/cyc L2 overload).
// Grid = 16 z * 16 tiles = 256 blocks = 1/CU; z XCD-affine.
// ---------------------------------------------------------------------------
__global__ __launch_bounds__(512, 2) void mfma_gemm_limb256(
    const _Float16* __restrict__ Ahi, const _Float16* __restrict__ Alo,
    const _Float16* __restrict__ Bhi, const _Float16* __restrict__ Blo,
    float* __restrict__ part, int K, int base, int extra)
{
    extern __shared__ __align__(16) char ldsraw[];   // 131072 bytes
    const int tid = threadIdx.x;
    const int lane = tid & 63;
    const int w = tid >> 6;            // 0..7
    const int wm = w >> 2, wn = w & 3; // wave tile: rows wm*128, cols wn*64
    const int kg = lane >> 4, lr = lane & 15;
    const int bid = blockIdx.x;
    const int z = bid & 15;
    const int tile = bid >> 4;
    const int bx = tile & 3, by = tile >> 2;
    const int row0 = by << 8, col0 = bx << 8;
    const int zsteps = base + (z < extra ? 1 : 0);
    const int kb0 = (z*base + (z < extra ? z : extra)) * 32;

    // staging: wave w owns plane w>>1 (0=Ah 1=Al 2=Bh 3=Bl), half (w&1)
    const int sp = w >> 1;
    const int sbase = (w & 1) * 8;
    const _Float16* pl = (sp == 0) ? Ahi : (sp == 1) ? Alo : (sp == 2) ? Bhi : Blo;
    const int rc0 = (sp < 2) ? row0 : col0;
    const _Float16* sG = pl + (size_t)(rc0 + lane)*K + kb0;

    f32x4 acc[8][4];
#pragma unroll
    for (int i = 0; i < 8; ++i)
#pragma unroll
        for (int j = 0; j < 4; ++j) acc[i][j] = (f32x4){0.f, 0.f, 0.f, 0.f};

    auto STAGE = [&](int bufoff, int koff) {
#pragma unroll
        for (int j = 0; j < 8; ++j) {
            int sub = sbase + j;           // 0..15: ks = sub>>2, rblk = sub&3
            int ks = sub >> 2, rblk = sub & 3;
            const void* g = (const void*)(sG + (size_t)(rblk*64)*K + koff + ks*8);
            void* l = (void*)(ldsraw + bufoff + sp*16384 + ks*4096 + rblk*1024);
            gload16(g, l);                 // dest uniform; HW adds lane*16
        }
    };

    STAGE(0, 0);
    if (zsteps > 1) STAGE(65536, 32);

    for (int t = 0; t < zsteps; ++t) {
        if (t + 1 < zsteps) asm volatile("s_waitcnt vmcnt(8)" ::: "memory");
        else                asm volatile("s_waitcnt vmcnt(0)" ::: "memory");
        __builtin_amdgcn_s_barrier();          // all waves' stage of tile t done
        asm volatile("" ::: "memory");         // pin reads below barrier
        const char* Lb = ldsraw + ((t & 1) ? 65536 : 0);
        f16x8 Bh[4], Bl[4];
#pragma unroll
        for (int ni = 0; ni < 4; ++ni) {
            int s = (kg*256 + wn*64 + ni*16 + lr) * 16;
            Bh[ni] = *(const f16x8*)(Lb + 2*16384 + s);
            Bl[ni] = *(const f16x8*)(Lb + 3*16384 + s);
        }
#pragma unroll
        for (int mi = 0; mi < 8; ++mi) {       // A reads fused under MFMA
            int s = (kg*256 + wm*128 + mi*16 + lr) * 16;
            f16x8 ah = *(const f16x8*)(Lb + s);
            f16x8 al = *(const f16x8*)(Lb + 16384 + s);
#pragma unroll
            for (int ni = 0; ni < 4; ++ni) {
                acc[mi][ni] = __builtin_amdgcn_mfma_f32_16x16x32_f16(ah, Bh[ni], acc[mi][ni], 0, 0, 0);
                acc[mi][ni] = __builtin_amdgcn_mfma_f32_16x16x32_f16(ah, Bl[ni], acc[mi][ni], 0, 0, 0);
                acc[mi][ni] = __builtin_amdgcn_mfma_f32_16x16x32_f16(al, Bh[ni], acc[mi][ni], 0, 0, 0);
            }
        }
        asm volatile("" ::: "memory");         // pin reads above barrier
        __builtin_amdgcn_s_barrier();          // all waves done reading buf
        asm volatile("" ::: "memory");         // pin STAGE below barrier
        if (t + 2 < zsteps) STAGE((t & 1) ? 65536 : 0, (t+2)*32);
    }

    // epilogue: C/D layout col=lane&15, row=(lane>>4)*4+j
    float* cb = part + ((size_t)z << 20)
              + (size_t)row0*HID + col0 + wn*64 + lr;
#pragma unroll
    for (int mi = 0; mi < 8; ++mi) {
#pragma unroll
        for (int j = 0; j < 4; ++j) {
            int row = wm*128 + mi*16 + kg*4 + j;
            float* pr = cb + (size_t)row*HID;
            pr[0]  = acc[mi][0][j];
            pr[16] = acc[mi][1][j];
            pr[32] = acc[mi][2][j];
            pr[48] = acc[mi][3][j];
        }
    }
}

// ---------------------------------------------------------------------------
// fc2 GEMM (r6 kernel, unchanged): 128x128 tile, depth-2 dbuf, counted vmcnt.
// ---------------------------------------------------------------------------
__global__ __launch_bounds__(256) void mfma_gemm_limb(
    const _Float16* __restrict__ Ahi, const _Float16* __restrict__ Alo,
    const _Float16* __restrict__ Bhi, const _Float16* __restrict__ Blo,
    float* __restrict__ part, int K, int base, int extra, int lognz)
{
    __shared__ __align__(16) _Float16 lds[2][4][512][8];   // 2 x 32KB
    const int tid = threadIdx.x;
    const int lane = tid & 63;
    const int w = tid >> 6, wm = w >> 1, wn = w & 1;
    const int kg = lane >> 4, lr = lane & 15;
    const int bid = blockIdx.x;
    const int nzm = (1 << lognz) - 1;
    const int z = bid & nzm;
    const int bx = (bid >> lognz) & 7;
    const int by = bid >> (lognz + 3);
    const int row0 = by << 7, col0 = bx << 7;
    const int zsteps = base + (z < extra ? 1 : 0);
    const int kb0 = (z*base + (z < extra ? z : extra)) * 32;
    const int r_ = tid & 127;
    const int ks1 = tid >> 7;          // 0 or 1
    const int wb = tid & 192;          // wave-uniform slot base

    const _Float16* srcA0 = Ahi + (size_t)(row0 + r_) * K + kb0 + ks1*8;
    const _Float16* srcA1 = Alo + (size_t)(row0 + r_) * K + kb0 + ks1*8;
    const _Float16* srcB0 = Bhi + (size_t)(col0 + r_) * K + kb0 + ks1*8;
    const _Float16* srcB1 = Blo + (size_t)(col0 + r_) * K + kb0 + ks1*8;

    f32x4 acc[4][4];
#pragma unroll
    for (int i = 0; i < 4; ++i)
#pragma unroll
        for (int j = 0; j < 4; ++j) acc[i][j] = (f32x4){0.f, 0.f, 0.f, 0.f};

#define STAGE(bf, off) do { \
    _Float16* Lb = &lds[bf][0][0][0]; \
    gload16(srcA0 + (off),      (void*)(Lb + (0*512 +       wb)*8)); \
    gload16(srcA0 + (off) + 16, (void*)(Lb + (0*512 + 256 + wb)*8)); \
    gload16(srcA1 + (off),      (void*)(Lb + (1*512 +       wb)*8)); \
    gload16(srcA1 + (off) + 16, (void*)(Lb + (1*512 + 256 + wb)*8)); \
    gload16(srcB0 + (off),      (void*)(Lb + (2*512 +       wb)*8)); \
    gload16(srcB0 + (off) + 16, (void*)(Lb + (2*512 + 256 + wb)*8)); \
    gload16(srcB1 + (off),      (void*)(Lb + (3*512 +       wb)*8)); \
    gload16(srcB1 + (off) + 16, (void*)(Lb + (3*512 + 256 + wb)*8)); \
} while (0)

    STAGE(0, 0);
    if (1 < zsteps) STAGE(1, 32);
    for (int t = 0; t < zsteps; ++t) {
        if (t + 1 < zsteps) asm volatile("s_waitcnt vmcnt(8)" ::: "memory");
        else                asm volatile("s_waitcnt vmcnt(0)" ::: "memory");
        __builtin_amdgcn_s_barrier();
        const _Float16* Lr = &lds[t & 1][0][0][0];
        f16x8 Ah[4], Al[4], Bh[4], Bl[4];
#pragma unroll
        for (int mi = 0; mi < 4; ++mi) {
            int s = kg*128 + wm*64 + mi*16 + lr;
            Ah[mi] = *(const f16x8*)(Lr + (0*512 + s)*8);
            Al[mi] = *(const f16x8*)(Lr + (1*512 + s)*8);
        }
#pragma unroll
        for (int ni = 0; ni < 4; ++ni) {
            int s = kg*128 + wn*64 + ni*16 + lr;
            Bh[ni] = *(const f16x8*)(Lr + (2*512 + s)*8);
            Bl[ni] = *(const f16x8*)(Lr + (3*512 + s)*8);
        }
        asm volatile("s_waitcnt lgkmcnt(0)" ::: "memory");   // frag data in regs
        __builtin_amdgcn_sched_barrier(0);
        __builtin_amdgcn_s_barrier();                        // all waves done reading
        if (t + 2 < zsteps) STAGE(t & 1, (t+2)*32);          // overwrite just-read buf
#pragma unroll
        for (int mi = 0; mi < 4; ++mi)
#pragma unroll
            for (int ni = 0; ni < 4; ++ni) {
                acc[mi][ni] = __builtin_amdgcn_mfma_f32_16x16x32_f16(Ah[mi], Bh[ni], acc[mi][ni], 0, 0, 0);
                acc[mi][ni] = __builtin_amdgcn_mfma_f32_16x16x32_f16(Ah[mi], Bl[ni], acc[mi][ni], 0, 0, 0);
                acc[mi][ni] = __builtin_amdgcn_mfma_f32_16x16x32_f16(Al[mi], Bh[ni], acc[mi][ni], 0, 0, 0);
            }
    }
#undef STAGE

    // epilogue: C/D layout col=lane&15, row=(lane>>4)*4+j
    float* cb = part + ((size_t)z << 20)
              + (size_t)row0*HID + col0 + wn*64 + lr;
#pragma unroll
    for (int mi = 0; mi < 4; ++mi) {
#pragma unroll
        for (int j = 0; j < 4; ++j) {
            int row = wm*64 + mi*16 + kg*4 + j;
            float* pr = cb + (size_t)row*HID;
            pr[0]  = acc[mi][0][j];
            pr[16] = acc[mi][1][j];
            pr[32] = acc[mi][2][j];
            pr[48] = acc[mi][3][j];
        }
    }
}

// out = relu(sum_p part[p]/2048 + bias); mode 0: fp32 out; mode 1: f16 limb out (x32)
__global__ __launch_bounds__(256) void reduce_bias_relu(
    const float* __restrict__ part, const float* __restrict__ bias,
    float* __restrict__ out32, _Float16* __restrict__ outhi, _Float16* __restrict__ outlo,
    int nsplit, int mode)
{
    int gid = blockIdx.x*256 + threadIdx.x;
    float s = 0.f;
    for (int p = 0; p < nsplit; ++p) s += part[((size_t)p << 20) + gid];
    s = s * (1.0f/2048.0f) + bias[gid & (HID-1)];
    s = fmaxf(s, 0.f);
    if (mode == 0) {
        out32[gid] = s;
    } else {
        float vs = s * 32.0f;
        _Float16 h = (_Float16)vs;
        outhi[gid] = h;
        outlo[gid] = (_Float16)(vs - (float)h);
    }
}

// cls+bbox heads + decode (+softmax at last stage). 4 rows per block.
__global__ __launch_bounds__(512) void heads_kernel(
    const float* __restrict__ X, const float* __restrict__ cwT, const float* __restrict__ cb,
    const float* __restrict__ bwT, const float* __restrict__ bbb,
    float* __restrict__ cur, float* __restrict__ probs,
    const int* __restrict__ img_sz, int stage, int write_probs)
{
    __shared__ float xs[4][1024];
    __shared__ float lg[4][96];
    int tid = threadIdx.x;
    int lr = tid >> 7;           // local row 0..3
    int j  = tid & 127;
    int row0 = blockIdx.x * 4;
    for (int i = tid; i < 4096; i += 512)
        xs[i >> 10][i & 1023] = X[(size_t)(row0 + (i >> 10))*1024 + (i & 1023)];
    __syncthreads();
    int row = row0 + lr;
    if (j < 85) {
        const float* wrow = (j < 81) ? (cwT + (size_t)j*HID) : (bwT + (size_t)(j-81)*HID);
        float acc = (j < 81) ? cb[j] : bbb[j-81];
        const float4* w4 = (const float4*)wrow;
#pragma unroll 4
        for (int k4 = 0; k4 < 256; ++k4) {
            float4 wv = w4[k4];
            const float* xr = &xs[lr][k4*4];
            acc = fmaf(xr[0], wv.x, acc);
            acc = fmaf(xr[1], wv.y, acc);
            acc = fmaf(xr[2], wv.z, acc);
            acc = fmaf(xr[3], wv.w, acc);
        }
        lg[lr][j] = acc;
    }
    __syncthreads();
    if (j == 0) {   // box decode + clip
        float img = (float)(*img_sz);
        float px1 = cur[row*4+0], py1 = cur[row*4+1];
        float px2 = cur[row*4+2], py2 = cur[row*4+3];
        float pw = fmaxf(px2-px1, 1e-6f), ph = fmaxf(py2-py1, 1e-6f);
        float pcx = px1 + 0.5f*pw, pcy = py1 + 0.5f*ph;
        float wx, wy, ww, wh;
        if (stage == 0)      { wx=0.1f;   wy=0.1f;   ww=0.2f;   wh=0.2f;   }
        else if (stage == 1) { wx=0.05f;  wy=0.05f;  ww=0.1f;   wh=0.1f;   }
        else                 { wx=0.033f; wy=0.033f; ww=0.067f; wh=0.067f; }
        float dx = lg[lr][81]*wx, dy = lg[lr][82]*wy;
        float dw = fminf(lg[lr][83]*ww, CLIPV);
        float dh = fminf(lg[lr][84]*wh, CLIPV);
        float cx = dx*pw + pcx, cy = dy*ph + pcy;
        float w = expf(dw)*pw, h = expf(dh)*ph;
        cur[row*4+0] = fminf(fmaxf(cx - 0.5f*w, 0.f), img);
        cur[row*4+1] = fminf(fmaxf(cy - 0.5f*h, 0.f), img);
        cur[row*4+2] = fminf(fmaxf(cx + 0.5f*w, 0.f), img);
        cur[row*4+3] = fminf(fmaxf(cy + 0.5f*h, 0.f), img);
    }
    if (write_probs) {
        if (j == 1) {
            float m = lg[lr][0];
            for (int c2 = 1; c2 < 81; ++c2) m = fmaxf(m, lg[lr][c2]);
            float s = 0.f;
            for (int c2 = 0; c2 < 81; ++c2) s += expf(lg[lr][c2] - m);
            lg[lr][88] = m; lg[lr][89] = s;
        }
        __syncthreads();
        if (j < 81)
            probs[(size_t)row*81 + j] = expf(lg[lr][j] - lg[lr][88]) / lg[lr][89];
    }
}

// bucket passing candidates per (image,class); cross-class IoU is exactly 0
// (label offset trick), so NMS decomposes per class.
__global__ __launch_bounds__(256) void compact_class(
    const float* __restrict__ probs, const float* __restrict__ cur,
    const int* __restrict__ img_sz, int* __restrict__ ccnt,
    float* __restrict__ ccs, float4* __restrict__ ccob, float* __restrict__ ccar,
    float4* __restrict__ ccbx, int* __restrict__ ccix)
{
    int gid = blockIdx.x*256 + threadIdx.x;
    if (gid >= NB*CAND_PER_IMG) return;
    int b = gid / CAND_PER_IMG;
    int rem = gid - b*CAND_PER_IMG;
    int n = rem / 80;
    int cm = rem - n*80;
    int label = cm + 1;
    int r = b*NPROP + n;
    float s = probs[(size_t)r*81 + label];
    float b0 = cur[r*4+0], b1 = cur[r*4+1], b2 = cur[r*4+2], b3 = cur[r*4+3];
    if (s > 0.05f && (b2 - b0) >= 1.0f && (b3 - b1) >= 1.0f) {
        int cls = b*80 + cm;
        int pos = atomicAdd(&ccnt[cls], 1);
        int base = cls*512 + pos;
        float img = (float)(*img_sz);
        float t = (float)label * (img + 2.0f);
        float o0 = b0+t, o1 = b1+t, o2 = b2+t, o3 = b3+t;
        ccs[base] = s;
        ccob[base] = make_float4(o0, o1, o2, o3);
        ccar[base] = fmaxf(o2-o0, 0.f) * fmaxf(o3-o1, 0.f);
        ccbx[base] = make_float4(b0, b1, b2, b3);
        ccix[base] = rem;   // reference flat order for tie-break
    }
}

// one wave per (image,class): greedy NMS entirely in registers
__global__ __launch_bounds__(64) void class_nms(
    const int* __restrict__ ccnt, const float* __restrict__ ccs,
    const float4* __restrict__ ccob, const float* __restrict__ ccar,
    const float4* __restrict__ ccbx, const int* __restrict__ ccix,
    float* __restrict__ svs, float4* __restrict__ svb, int* __restrict__ svi,
    int* __restrict__ svc)
{
    int cls = blockIdx.x;          // 0..159
    int Nc = ccnt[cls];
    int base = cls*512;
    int lane = threadIdx.x;
    __shared__ float sel[5];
    float s[8]; float4 ob[8]; float a[8]; int ix[8];
    int cntl = 0;
    for (int j = lane; j < Nc; j += 64) {
        s[cntl] = ccs[base+j]; ob[cntl] = ccob[base+j];
        a[cntl] = ccar[base+j]; ix[cntl] = ccix[base+j];
        ++cntl;
    }
    int svn = 0;
    int rounds = (Nc < 100) ? Nc : 100;
    for (int it = 0; it < rounds; ++it) {
        float bs = -1.f; int bi = 0x7fffffff;
        for (int q = 0; q < cntl; ++q)
            if (s[q] > bs || (s[q] == bs && ix[q] < bi)) { bs = s[q]; bi = ix[q]; }
        for (int off = 32; off > 0; off >>= 1) {
            float os = __shfl_xor(bs, off);
            int oi = __shfl_xor(bi, off);
            if (os > bs || (os == bs && oi < bi)) { bs = os; bi = oi; }
        }
        if (bs <= 0.f) break;      // uniform across wave
        for (int q = 0; q < cntl; ++q) {
            if (s[q] == bs && ix[q] == bi) {   // unique owner (ix unique)
                sel[0] = ob[q].x; sel[1] = ob[q].y; sel[2] = ob[q].z; sel[3] = ob[q].w;
                sel[4] = a[q];
                int slot = cls*128 + svn;
                svs[slot] = bs;
                svb[slot] = ccbx[base + lane + q*64];
                svi[slot] = bi;
                s[q] = -1.f;
            }
        }
        __syncthreads();
        float bi0 = sel[0], bi1 = sel[1], bi2 = sel[2], bi3 = sel[3], ai = sel[4];
        for (int q = 0; q < cntl; ++q) {
            if (s[q] > 0.f) {
                float ix1 = fmaxf(bi0, ob[q].x), iy1 = fmaxf(bi1, ob[q].y);
                float ix2 = fminf(bi2, ob[q].z), iy2 = fminf(bi3, ob[q].w);
                float inter = fmaxf(ix2-ix1, 0.f) * fmaxf(iy2-iy1, 0.f);
                float iou = inter / (ai + a[q] - inter + 1e-9f);
                if (iou > 0.5f) s[q] = -1.f;
            }
        }
        ++svn;
        __syncthreads();
    }
    if (lane == 0) svc[cls] = svn;
}

// per image: bitonic-sort survivors by (score desc, coidx asc), write top-100.
// key = (score_bits << 32) | (~coidx); invalid slots key=0 sort last.
__global__ __launch_bounds__(256) void merge_topk(
    const float* __restrict__ svs, const float4* __restrict__ svb,
    const int* __restrict__ svi, const int* __restrict__ svc,
    float* __restrict__ out)
{
    extern __shared__ char smem[];
    u64* keys = (u64*)smem;                 // [8192] 64KB
    u32* pay  = (u32*)(smem + 65536);       // [8192] 32KB
    __shared__ int off[81];
    __shared__ int n2s;
    int b = blockIdx.x, tid = threadIdx.x;
    if (tid == 0) {
        int run = 0;
        for (int c = 0; c < 80; ++c) { off[c] = run; run += svc[b*80 + c]; }
        off[80] = run;
        int n2 = 256;
        while (n2 < run) n2 <<= 1;
        n2s = n2;
    }
    __syncthreads();
    int Ns = off[80], n2 = n2s;
    for (int c = 0; c < 80; ++c) {
        int n = off[c+1] - off[c];
        int srcb = (b*80 + c)*128;
        for (int k = tid; k < n; k += 256) {
            int src = srcb + k;
            keys[off[c] + k] = ((u64)__float_as_uint(svs[src]) << 32)
                             | (u64)(0xFFFFFFFFu - (u32)svi[src]);
            pay[off[c] + k] = src;
        }
    }
    for (int i = Ns + tid; i < n2; i += 256) { keys[i] = 0; pay[i] = 0; }
    __syncthreads();
    for (int k = 2; k <= n2; k <<= 1) {
        for (int j = k >> 1; j > 0; j >>= 1) {
            for (int i = tid; i < n2; i += 256) {
                int l = i ^ j;
                if (l > i) {
                    u64 a = keys[i], bb = keys[l];
                    bool dir = ((i & k) == 0);
                    if ((a < bb) == dir) {
                        keys[i] = bb; keys[l] = a;
                        u32 p = pay[i]; pay[i] = pay[l]; pay[l] = p;
                    }
                }
            }
            __syncthreads();
        }
    }
    if (tid < 100) {
        u64 kk = keys[tid];      // n2 >= 256 > 100 always
        if (kk != 0) {
            u32 ci = 0xFFFFFFFFu - (u32)(kk & 0xFFFFFFFFull);
            float4 bx = svb[pay[tid]];
            out[b*400 + tid*4 + 0] = bx.x;
            out[b*400 + tid*4 + 1] = bx.y;
            out[b*400 + tid*4 + 2] = bx.z;
            out[b*400 + tid*4 + 3] = bx.w;
            out[800  + b*100 + tid] = __uint_as_float((u32)(kk >> 32));
            out[1000 + b*100 + tid] = (float)((ci % 80) + 1);
        } else {
            out[b*400 + tid*4 + 0] = 0.f; out[b*400 + tid*4 + 1] = 0.f;
            out[b*400 + tid*4 + 2] = 0.f; out[b*400 + tid*4 + 3] = 0.f;
            out[800  + b*100 + tid] = 0.f;
            out[1000 + b*100 + tid] = 0.f;
        }
    }
}

extern "C" void kernel_launch(void* const* d_in, const int* in_sizes, int n_in,
                              void* d_out, int out_size, void* d_ws, size_t ws_size,
                              hipStream_t stream)
{
    const float* features  = (const float*)d_in[0];
    const float* proposals = (const float*)d_in[1];
    const float* fc1_w = (const float*)d_in[2];
    const float* fc1_b = (const float*)d_in[3];
    const float* fc2_w = (const float*)d_in[4];
    const float* fc2_b = (const float*)d_in[5];
    const float* cls_w = (const float*)d_in[6];
    const float* cls_b = (const float*)d_in[7];
    const float* bbox_w = (const float*)d_in[8];
    const float* bbox_b = (const float*)d_in[9];
    const int* img_sz = (const int*)d_in[10];
    float* out = (float*)d_out;
    char* ws = (char*)d_ws;
    _Float16* xhi   = (_Float16*)(ws + XHI_OFF);
    _Float16* xlo   = (_Float16*)(ws + XLO_OFF);
    _Float16* wt1hi = (_Float16*)(ws + WT1HI_OFF);
    _Float16* wt1lo = (_Float16*)(ws + WT1LO_OFF);
    _Float16* wt2hi = (_Float16*)(ws + WT2HI_OFF);
    _Float16* wt2lo = (_Float16*)(ws + WT2LO_OFF);
    _Float16* h1hi  = (_Float16*)(ws + H1HI_OFF);
    _Float16* h1lo  = (_Float16*)(ws + H1LO_OFF);
    float*  h2     = (float*) (ws + H2_OFF);
    float*  cwT    = (float*) (ws + CWT_OFF);
    float*  bwT    = (float*) (ws + BWT_OFF);
    float*  probs  = (float*) (ws + PROBS_OFF);
    float*  cur    = (float*) (ws + CUR_OFF);
    int*    ccnt   = (int*)   (ws + CNT_OFF);
    float*  ccs    = (float*) (ws + CCS_OFF);
    float4* ccob   = (float4*)(ws + CCOB_OFF);
    float*  ccar   = (float*) (ws + CCAR_OFF);
    float4* ccbx   = (float4*)(ws + CCBX_OFF);
    int*    ccix   = (int*)   (ws + CCIX_OFF);
    float*  svs    = (float*) (ws + SVS_OFF);
    float4* svb    = (float4*)(ws + SVB_OFF);
    int*    svi    = (int*)   (ws + SVI_OFF);
    int*    svc    = (int*)   (ws + SVC_OFF);
    float*  part   = (float*) (ws + PART_OFF);

    init_kernel<<<1, 256, 0, stream>>>(ccnt);
    hipMemcpyAsync(cur, proposals, (size_t)NROWS*4*sizeof(float),
                   hipMemcpyDeviceToDevice, stream);
    trans_naive<<<(3*NCLS*HID + 255)/256, 256, 0, stream>>>(cls_w, cwT, HID, NCLS, 3);
    trans_naive<<<(3*4*HID + 255)/256, 256, 0, stream>>>(bbox_w, bwT, HID, 4, 3);

    for (int st = 0; st < 3; ++st) {
        roi_align_kernel<<<NROWS, 256, 0, stream>>>(features, cur, xhi, xlo);
        trans_limb<<<dim3(HID/32, INDIM/32), 256, 0, stream>>>(
            fc1_w + (size_t)st*INDIM*HID, wt1hi, wt1lo, INDIM, HID, 64.0f);
        // fc1: 392 K-steps; z=16 (8 z's x 25 steps + 8 x 24); 256 blocks = 1/CU
        mfma_gemm_limb256<<<256, 512, 131072, stream>>>(
            xhi, xlo, wt1hi, wt1lo, part, INDIM, 24, 8);
        reduce_bias_relu<<<(NROWS*HID)/256, 256, 0, stream>>>(
            part, fc1_b + st*HID, nullptr, h1hi, h1lo, 16, 1);
        trans_limb<<<dim3(HID/32, HID/32), 256, 0, stream>>>(
            fc2_w + (size_t)st*HID*HID, wt2hi, wt2lo, HID, HID, 64.0f);
        // fc2: K=1024 = 32 K-steps; z=8 x 4 steps
        mfma_gemm_limb<<<512, 256, 0, stream>>>(
            h1hi, h1lo, wt2hi, wt2lo, part, HID, 4, 0, 3);
        reduce_bias_relu<<<(NROWS*HID)/256, 256, 0, stream>>>(
            part, fc2_b + st*HID, h2, nullptr, nullptr, 8, 0);
        heads_kernel<<<NROWS/4, 512, 0, stream>>>(
            h2, cwT + (size_t)st*NCLS*HID, cls_b + st*NCLS,
            bwT + (size_t)st*4*HID, bbox_b + st*4,
            cur, probs, img_sz, st, st == 2 ? 1 : 0);
    }
    compact_class<<<(NB*CAND_PER_IMG)/256, 256, 0, stream>>>(
        probs, cur, img_sz, ccnt, ccs, ccob, ccar, ccbx, ccix);
    class_nms<<<160, 64, 0, stream>>>(
        ccnt, ccs, ccob, ccar, ccbx, ccix, svs, svb, svi, svc);
    merge_topk<<<NB, 256, 98304, stream>>>(
        svs, svb, svi, svc, out);
}